// Round 1
// 181.710 us; speedup vs baseline: 1.0124x; 1.0124x over previous
//
#include <hip/hip_runtime.h>

// Round 5: drop the per-block LDS staging of M in forward_k.
// Rationale: M is 15.4 KB — it fits in each CU's 32 KiB L1. Staging it into
// LDS in all 1024 blocks was a 15.7 MB aggregate LDS round-trip plus a full
// barrier drain, and the 32.3 KB LDS footprint capped occupancy at 4
// blocks/CU. Phase A's chunk-major M layout (lane j reads contiguous 16 B at
// Mg[ch*248 + j*4]) is perfectly coalesced as a direct global load and
// L1-hot after first touch per CU. LDS now 16.9 KB/block (Xs + Ys only).

#define NE 62
#define IC 5
#define NTRIL 1953
#define SA 68               // internal row stride in build_M's LDS
#define MTOT 3844           // floats in chunk-major M: 15*248 + 124
// Chunk-major M layout: for ch<15: Mc[ch*248 + j*4 + k] = M[j][4ch+k]
//                        tail:     Mc[3720 + j*2 + k]   = M[j][60+k]
// Forward-phase-A lane j reads contiguous 16B per lane -> fully coalesced.

// Kernel 1: M = (D^-1/2 A D^-1/2)^2 from the 1953 lower-tri params.
__global__ __launch_bounds__(256) void build_M(const float* __restrict__ adj_tril,
                                               float* __restrict__ Mg) {
    __shared__ float A[NE * SA];
    __shared__ float dinv[NE];
    int tid = threadIdx.x;
    for (int t = tid; t < NTRIL; t += 256) {
        float v = adj_tril[t];
        float r = sqrtf((float)(8 * t + 1));
        int i = (int)((r - 1.0f) * 0.5f);
        while ((i + 1) * (i + 2) / 2 <= t) ++i;
        while (i * (i + 1) / 2 > t) --i;
        int j = t - i * (i + 1) / 2;
        A[i * SA + j] = v;
        A[j * SA + i] = v;
    }
    __syncthreads();
    if (tid < NE) {
        float s = 0.f;
        for (int k = 0; k < NE; ++k) s += fabsf(A[tid * SA + k]);
        dinv[tid] = (s > 0.f) ? rsqrtf(s) : 0.f;
    }
    __syncthreads();
    for (int g = tid; g < NE * NE; g += 256) {
        int i = g / NE, j = g % NE;
        A[i * SA + j] *= dinv[i] * dinv[j];
    }
    __syncthreads();
    int g = blockIdx.x * 256 + tid;
    if (g < NE * NE) {
        int r = g / NE, cidx = g % NE;   // M[r][cidx] = dot(An row r, An row cidx)
        const float4* ra = (const float4*)(A + r * SA);
        const float4* rb = (const float4*)(A + cidx * SA);
        float acc = 0.f;
#pragma unroll
        for (int c = 0; c < 15; ++c) {
            float4 a = ra[c], b = rb[c];
            acc += a.x * b.x + a.y * b.y + a.z * b.z + a.w * b.w;
        }
        acc += A[r * SA + 60] * A[cidx * SA + 60] + A[r * SA + 61] * A[cidx * SA + 61];
        int addr = (cidx < 60) ? ((cidx >> 2) * 248 + r * 4 + (cidx & 3))
                               : (3720 + r * 2 + (cidx - 60));
        Mg[addr] = acc;
    }
}

// Kernel 2: per-graph forward, one wave per graph (1024 blocks x 4 waves).
__global__ __launch_bounds__(256) void forward_k(const float* __restrict__ x,
        const float* __restrict__ lin_w, const float* __restrict__ lin_b,
        const float* __restrict__ fc_w, const float* __restrict__ fc_b,
        const float* __restrict__ Mg, float* __restrict__ out) {
    __shared__ float Xs[4 * 312];         // 310 floats/graph, padded to 312 (16B align)
    __shared__ float Ys[4][NE * 12];      // per-wave Y; phase-B reads are broadcasts
    int tid = threadIdx.x;
    // ---- coalesced X staging only (M is read direct from global: L1-hot) ----
    {
        const float2* xsrc = (const float2*)(x + (size_t)blockIdx.x * (4 * 310));
        for (int t = tid; t < 620; t += 256) {          // 155 float2 per graph
            int w = t / 155, o = t - w * 155;
            *(float2*)&Xs[w * 312 + o * 2] = xsrc[t];
        }
    }
    int wid = tid >> 6;
    int lane = tid & 63;
    int b = blockIdx.x * 4 + wid;
    int c = lane & 31;
    float w0 = lin_w[c * 5 + 0], w1 = lin_w[c * 5 + 1], w2 = lin_w[c * 5 + 2],
          w3 = lin_w[c * 5 + 3], w4 = lin_w[c * 5 + 4];
    float lb = lin_b[c];
    float f0 = fc_w[c], f1 = fc_w[32 + c], f2 = fc_w[64 + c];
    __syncthreads();
    // ---- phase A: lane j computes Y[j,0:5] = sum_i M[j,i] * X[i,0:5] ----
    int j = lane;
    if (j < NE) {
        const float* xb = Xs + wid * 312;
        float y0 = 0, y1 = 0, y2 = 0, y3 = 0, y4 = 0;
#pragma unroll
        for (int ch = 0; ch < 15; ++ch) {
            float4 m = *(const float4*)(Mg + ch * 248 + j * 4);     // coalesced, L1-hot
            const float4* xi = (const float4*)(xb + ch * 20);       // wave-uniform bcast
            float4 xa = xi[0], xv = xi[1], xc = xi[2], xd = xi[3], xe = xi[4];
            y0 += m.x * xa.x; y1 += m.x * xa.y; y2 += m.x * xa.z; y3 += m.x * xa.w; y4 += m.x * xv.x;
            y0 += m.y * xv.y; y1 += m.y * xv.z; y2 += m.y * xv.w; y3 += m.y * xc.x; y4 += m.y * xc.y;
            y0 += m.z * xc.z; y1 += m.z * xc.w; y2 += m.z * xd.x; y3 += m.z * xd.y; y4 += m.z * xd.z;
            y0 += m.w * xd.w; y1 += m.w * xe.x; y2 += m.w * xe.y; y3 += m.w * xe.z; y4 += m.w * xe.w;
        }
        float2 mt = *(const float2*)(Mg + 3720 + j * 2);            // coalesced 8B
        const float* xt = xb + 300;
        y0 += mt.x * xt[0] + mt.y * xt[5];
        y1 += mt.x * xt[1] + mt.y * xt[6];
        y2 += mt.x * xt[2] + mt.y * xt[7];
        y3 += mt.x * xt[3] + mt.y * xt[8];
        y4 += mt.x * xt[4] + mt.y * xt[9];
        float* yr = &Ys[wid][j * 12];
        *(float4*)yr = make_float4(y0, y1, y2, y3);
        yr[4] = y4;
    }
    __syncthreads();
    // ---- phase B: lane (half,c) accumulates relu(Y[j]·W[c]+b[c]) over its j-half ----
    int half = lane >> 5;
    float acc = 0.f;
    int jbeg = half * 31;
    for (int t = 0; t < 31; ++t) {
        const float* yr = &Ys[wid][(jbeg + t) * 12];   // same addr across half: bcast
        float4 yv = *(const float4*)yr;
        float d = yv.x * w0 + yv.y * w1 + yv.z * w2 + yv.w * w3 + yr[4] * w4 + lb;
        acc += fmaxf(d, 0.f);
    }
    acc += __shfl_xor(acc, 32, 64);   // combine j-halves; all lanes hold pooled[c]
    // ---- head ----
    float p0 = acc * f0, p1 = acc * f1, p2 = acc * f2;
#pragma unroll
    for (int m = 16; m >= 1; m >>= 1) {
        p0 += __shfl_xor(p0, m, 64);
        p1 += __shfl_xor(p1, m, 64);
        p2 += __shfl_xor(p2, m, 64);
    }
    if (lane == 0) {
        out[b * 3 + 0] = p0 + fc_b[0];
        out[b * 3 + 1] = p1 + fc_b[1];
        out[b * 3 + 2] = p2 + fc_b[2];
    }
}

extern "C" void kernel_launch(void* const* d_in, const int* in_sizes, int n_in,
                              void* d_out, int out_size, void* d_ws, size_t ws_size,
                              hipStream_t stream) {
    const float* x        = (const float*)d_in[0];
    const float* adj_tril = (const float*)d_in[1];
    const float* lin_w    = (const float*)d_in[2];
    const float* lin_b    = (const float*)d_in[3];
    const float* fc_w     = (const float*)d_in[4];
    const float* fc_b     = (const float*)d_in[5];
    // d_in[6]=edge_index, d_in[7]=batch_idx: structurally redundant (dense
    // all-pairs per-graph) — never read.
    float* out = (float*)d_out;
    float* Mg  = (float*)d_ws;   // 3844 floats of scratch

    build_M<<<16, 256, 0, stream>>>(adj_tril, Mg);
    forward_k<<<1024, 256, 0, stream>>>(x, lin_w, lin_b, fc_w, fc_b, Mg, out);
}